// Round 24
// baseline (90.763 us; speedup 1.0000x reference)
//
#include <hip/hip_runtime.h>
#include <math.h>

#define BB 4096        // batch size
#define DD 512         // repr dim
#define KTOP 9         // K+1
#define MARGIN_F 0.2f
#define NT 32          // 4096/128
#define NTRI (NT * (NT + 1) / 2)   // 528 upper-triangle 128x128 blocks

typedef __attribute__((ext_vector_type(8))) short short8;
typedef __attribute__((ext_vector_type(4))) float f32x4;
typedef unsigned long long u64;

__device__ unsigned short g_Rhi[(size_t)BB * DD];
__device__ unsigned short g_Rpk[(size_t)BB * DD];   // panel-major MFMA-fragment layout
__device__ u64 g_cmask[64 * 64];   // [class][lane] bit e -> label[j(lane,e)]==class

// ---- bf16 helper (RNE) ----
__device__ __forceinline__ unsigned short f2bf(float x) {
  unsigned u = __float_as_uint(x);
  u += 0x7fffu + ((u >> 16) & 1u);
  return (unsigned short)(u >> 16);
}

// ---- 16-bit ord: monotone map of f32, truncated; dequant mid-bucket ----
__device__ __forceinline__ float ord16val(unsigned o16) {
  unsigned e = (o16 << 16) | 0x8000u;
  unsigned s = (e & 0x80000000u) ? (e ^ 0x80000000u) : ~e;
  return __uint_as_float(s);
}

// ---- DPP wave reductions ----
__device__ __forceinline__ unsigned wavemax32_dpp(unsigned c) {
#define MSTEP(CTRL, RM)                                                        \
  {                                                                            \
    unsigned o = (unsigned)__builtin_amdgcn_update_dpp(0, (int)c, CTRL, RM, 0xf, false); \
    if (o > c) c = o;                                                          \
  }
  MSTEP(0xB1, 0xf) MSTEP(0x4E, 0xf) MSTEP(0x141, 0xf) MSTEP(0x140, 0xf)
  MSTEP(0x142, 0xa) MSTEP(0x143, 0xc)
#undef MSTEP
  return (unsigned)__builtin_amdgcn_readlane((int)c, 63);
}

__device__ __forceinline__ int wavesum_dpp(int c) {
#define SSTEP(CTRL, RM)                                                        \
  c += __builtin_amdgcn_update_dpp(0, c, CTRL, RM, 0xf, false);
  SSTEP(0xB1, 0xf) SSTEP(0x4E, 0xf) SSTEP(0x141, 0xf) SSTEP(0x140, 0xf)
  SSTEP(0x142, 0xa) SSTEP(0x143, 0xc)
#undef SSTEP
  return __builtin_amdgcn_readlane(c, 63);
}

__device__ __forceinline__ unsigned u4c(const uint4& f, int q) {
  return q == 0 ? f.x : q == 1 ? f.y : q == 2 ? f.z : f.w;
}

// ---------------- K0: split R -> bf16 hi + row sqnorms ----------------
__global__ __launch_bounds__(64) void splitsq(const float* __restrict__ R,
                                              float* __restrict__ sq) {
  const int row = blockIdx.x, lane = threadIdx.x;
  const float4* r4 = (const float4*)(R + (size_t)row * DD);
  float4 a = r4[lane], b = r4[lane + 64];
  float xs[8] = {a.x, a.y, a.z, a.w, b.x, b.y, b.z, b.w};
  unsigned short hs[8];
  float s = 0.f;
  #pragma unroll
  for (int q = 0; q < 8; ++q) {
    float x = xs[q];
    s += x * x;
    hs[q] = f2bf(x);
  }
  const size_t base = (size_t)row * DD;
  *(ushort4*)&g_Rhi[base + lane * 4]       = *(ushort4*)&hs[0];
  *(ushort4*)&g_Rhi[base + 256 + lane * 4] = *(ushort4*)&hs[4];
  #pragma unroll
  for (int off = 32; off; off >>= 1) s += __shfl_down(s, off);
  if (lane == 0) sq[row] = s;
}

// ---------------- K0a: repack hi into panel-major MFMA fragment layout ----------------
__global__ __launch_bounds__(256) void repack(void) {
  const int p = blockIdx.x;
  #pragma unroll
  for (int i = 0; i < 4; ++i) {
    const int idx = i * 256 + threadIdx.x;
    const int ks = idx >> 6, l = idx & 63;
    const int row = p * 16 + (l & 15);
    const int k0 = ks * 32 + (l >> 4) * 8;
    *(uint4*)&g_Rpk[(size_t)p * 8192 + (size_t)idx * 8] =
        *(const uint4*)&g_Rhi[(size_t)row * DD + k0];
  }
}

// ---------------- K0b: per-class match bitmasks ----------------
__global__ __launch_bounds__(64) void buildmask(const int* __restrict__ labels) {
  __shared__ int slab[BB];
  const int c = blockIdx.x, lane = threadIdx.x;
  for (int i = lane; i < BB / 4; i += 64) ((int4*)slab)[i] = ((const int4*)labels)[i];
  __syncthreads();
  u64 m = 0;
  #pragma unroll
  for (int e = 0; e < 64; ++e) {
    int j = 512 * (e >> 3) + 8 * lane + (e & 7);
    m |= (u64)(slab[j] == c) << e;
  }
  g_cmask[c * 64 + lane] = m;
}

// ---------------- K1: panel-packed BARRIER-FREE MFMA GEMM (R22 best-known) ----------------
__global__ __launch_bounds__(256, 2) void simgemm_pk(const int* __restrict__ labels,
                                                     const float* __restrict__ sq,
                                                     unsigned short* __restrict__ simq) {
  const int x = blockIdx.x & 7;      // XCD (round-robin dispatch)
  int c = blockIdx.x >> 3;           // 0..65 within XCD
  int bi = 0, bj = 0;
  #pragma unroll
  for (int q = 0; q < 4; ++q) {
    const int bjq = (q < 2) ? (2 * x + q) : (28 - 2 * x + q);   // {2x,2x+1,30-2x,31-2x}
    const int n = bjq + 1;
    if (c >= 0 && c < n) { bj = bjq; bi = c; }
    c -= n;
  }
  const int i0 = bi * 128, j0 = bj * 128;

  __shared__ __align__(16) unsigned char smembytes[35840];   // epilogue only

  const int tid = threadIdx.x;
  const int wid = tid >> 6, lane = tid & 63;
  const int wr = wid >> 1, wc = wid & 1;
  const int lrow = lane & 15, kblk = lane >> 4;

  const unsigned short* pA[4];
  const unsigned short* pB[4];
  #pragma unroll
  for (int m = 0; m < 4; ++m) {
    pA[m] = g_Rpk + (size_t)(bi * 8 + wr * 4 + m) * 8192 + lane * 8;
    pB[m] = g_Rpk + (size_t)(bj * 8 + wc * 4 + m) * 8192 + lane * 8;
  }

  f32x4 acc[4][4] = {};
  short8 fa[2][4], fb[2][4];

  #pragma unroll
  for (int m = 0; m < 4; ++m) {
    fa[0][m] = *(const short8*)(pA[m]);
    fb[0][m] = *(const short8*)(pB[m]);
  }

  #pragma unroll
  for (int step = 0; step < 16; ++step) {
    const int cur = step & 1;
    if (step < 15) {
      const int koff = (step + 1) * 512;
      #pragma unroll
      for (int m = 0; m < 4; ++m) {
        fa[cur ^ 1][m] = *(const short8*)(pA[m] + koff);
        fb[cur ^ 1][m] = *(const short8*)(pB[m] + koff);
      }
    }
    #pragma unroll
    for (int m = 0; m < 4; ++m) {
      #pragma unroll
      for (int n = 0; n < 4; ++n) {
        acc[m][n] = __builtin_amdgcn_mfma_f32_16x16x32_bf16(fa[cur][m], fb[cur][n], acc[m][n], 0, 0, 0);
      }
    }
  }

  unsigned short (*T)[132] = (unsigned short (*)[132])smembytes;   // 33792 B
  float* sqi = (float*)(smembytes + 33792);
  float* sqj = (float*)(smembytes + 34304);
  int* labi  = (int*)(smembytes + 34816);
  int* labj  = (int*)(smembytes + 35328);
  if (tid < 128) { sqi[tid] = sq[i0 + tid]; labi[tid] = labels[i0 + tid]; }
  else { int t2 = tid - 128; sqj[t2] = sq[j0 + t2]; labj[t2] = labels[j0 + t2]; }
  __syncthreads();

  #pragma unroll
  for (int m = 0; m < 4; ++m) {
    const int rbase = wr * 64 + m * 16 + kblk * 4;
    #pragma unroll
    for (int n = 0; n < 4; ++n) {
      const int ccol = wc * 64 + n * 16 + lrow;
      const float sqc = sqj[ccol];
      const int lc_ = labj[ccol];
      #pragma unroll
      for (int reg = 0; reg < 4; ++reg) {
        const int r = rbase + reg;
        float res = sqi[r] - 2.0f * acc[m][n][reg] + sqc;
        float dd = (res <= 0.f) ? 0.f : sqrtf(res);
        float sv = -dd + ((labi[r] != lc_) ? MARGIN_F : 0.f);
        unsigned su = __float_as_uint(sv);
        unsigned ord = su ^ ((unsigned)((int)su >> 31) | 0x80000000u);
        T[r][ccol] = (unsigned short)(ord >> 16);
      }
    }
  }
  __syncthreads();

  const int srow0 = tid >> 4, scol0 = (tid & 15) * 8;
  #pragma unroll
  for (int p = 0; p < 8; ++p) {
    const int r = p * 16 + srow0;
    short8 w = *(const short8*)&T[r][scol0];
    *(short8*)&simq[(size_t)(i0 + r) * BB + j0 + scol0] = w;
  }
  if (bi != bj) {
    #pragma unroll
    for (int p = 0; p < 8; ++p) {
      const int col = p * 16 + srow0;
      unsigned short tmp[8];
      #pragma unroll
      for (int t = 0; t < 8; ++t) tmp[t] = T[scol0 + t][col];
      *(short8*)&simq[(size_t)(j0 + col) * BB + i0 + scol0] = *(short8*)tmp;
    }
  }
}

// ---------------- K2: rank processing, 2 waves/row, LOCAL pops + 9-way merge ----------------
// Each wave pops its local top-9 (and local top-fpn FN candidates) purely with
// DPP -- no barriers. The two sorted lists merge in a 2-pointer loop (heads
// read from LDS with runtime index; register arrays only statically indexed).
// Barriers per row: 20 (R21) -> 4.
#define TOP2UPD(k, a, b) {                                                     \
  unsigned _mx = ((k) > (a)) ? (k) : (a);                                      \
  unsigned _mn = ((k) > (a)) ? (a) : (k);                                      \
  (a) = _mx;                                                                   \
  (b) = (_mn > (b)) ? _mn : (b); }

__global__ __launch_bounds__(128) void rowproc10(const unsigned short* __restrict__ simq,
                                                 const int* __restrict__ labels,
                                                 float* __restrict__ partials) {
  __shared__ unsigned sl[2][KTOP];
  __shared__ unsigned sf[2][KTOP];
  __shared__ int spos[2];
  __shared__ int scnt[2][KTOP];

  const int tid = threadIdx.x;
  const int lane = tid & 63;
  const int h = tid >> 6;                     // wave 0/1
  const int row = blockIdx.x;

  const uint4* rp = (const uint4*)(simq + (size_t)row * BB);
  uint4 w0 = rp[lane + (4 * h + 0) * 64];
  uint4 w1 = rp[lane + (4 * h + 1) * 64];
  uint4 w2 = rp[lane + (4 * h + 2) * 64];
  uint4 w3 = rp[lane + (4 * h + 3) * 64];

  const int myl = labels[row];
  const unsigned mh = (unsigned)(g_cmask[myl * 64 + lane] >> (32 * h));
  const unsigned lbase2 = (unsigned)((4095 - 8 * lane) << 1);

  unsigned k[32];
  #pragma unroll
  for (int s = 0; s < 4; ++s) {
    const uint4 w = s == 0 ? w0 : s == 1 ? w1 : s == 2 ? w2 : w3;
    const unsigned base_s = lbase2 - (unsigned)(1024 * (4 * h + s));
    #pragma unroll
    for (int q = 0; q < 4; ++q) {
      const unsigned wv = u4c(w, q);
      const int e0 = s * 8 + q * 2;
      k[e0]     = ((wv & 0xffffu) << 13)
                | (base_s - (unsigned)((q * 2) << 1)     + ((mh >> e0) & 1u));
      k[e0 + 1] = ((wv >> 16) << 13)
                | (base_s - (unsigned)((q * 2 + 1) << 1) + ((mh >> (e0 + 1)) & 1u));
    }
  }

  {
    int p = wavesum_dpp(__popc(mh));
    if (lane == 0) spos[h] = p;
  }

  // ---- local top-9 pops (no barriers) ----
  unsigned h1 = 0, h2 = 0;
  #pragma unroll
  for (int e = 0; e < 32; ++e) TOP2UPD(k[e], h1, h2);
  #pragma unroll
  for (int t = 0; t < KTOP; ++t) {
    const unsigned g = wavemax32_dpp(h1);
    if (lane == 0) sl[h][t] = g;
    if (h1 == g) {
      h1 = h2; h2 = ~0u;
      if (h1 == ~0u) {
        h1 = 0; h2 = 0;
        #pragma unroll
        for (int e = 0; e < 32; ++e) {
          if (k[e] < g) TOP2UPD(k[e], h1, h2);
        }
      }
    }
  }
  __syncthreads();   // [1] local lists + pos visible

  const int pos = spos[0] + spos[1];
  const int ks = min(pos, KTOP);

  // ---- merge two sorted desc lists: fp, fpn, kth ----
  float fp = 0.f; int fpn = 0; unsigned kth = 0;
  {
    int ia = 0, ib = 0;
    #pragma unroll
    for (int t = 0; t < KTOP; ++t) {
      if (t < ks) {
        const unsigned va = (ia < KTOP) ? sl[0][ia] : 0u;
        const unsigned vb = (ib < KTOP) ? sl[1][ib] : 0u;
        unsigned m;
        if (va >= vb) { m = va; ++ia; } else { m = vb; ++ib; }
        if (!(m & 1u)) { fp += ord16val(m >> 13) * (1.f / log2f((float)(t + 2)) + 1.f); fpn++; }
        if (t == ks - 1) kth = m;
      }
    }
  }

  // ---- fn: local top-fpn same-class-below-kth pops, merge, fused count ----
  float fn = 0.f;
  if (fpn > 0) {                               // fpn block-uniform
    unsigned f1 = 0, f2 = 0;
    #pragma unroll
    for (int e = 0; e < 32; ++e) {
      if ((k[e] & 1u) && k[e] < kth) TOP2UPD(k[e], f1, f2);
    }
    #pragma unroll
    for (int u = 0; u < KTOP; ++u) {
      unsigned g = 0;
      if (u < fpn) {
        g = wavemax32_dpp(f1);
        if (g != 0u && f1 == g) {
          f1 = f2; f2 = ~0u;
          if (f1 == ~0u) {
            f1 = 0; f2 = 0;
            #pragma unroll
            for (int e = 0; e < 32; ++e) {
              if ((k[e] & 1u) && k[e] < g) TOP2UPD(k[e], f1, f2);
            }
          }
        }
      }
      if (lane == 0) sf[h][u] = g;
    }
    __syncthreads();   // [2] fn lists visible

    unsigned ck[KTOP];
    int nc = 0;
    {
      int ia = 0, ib = 0;
      #pragma unroll
      for (int u = 0; u < KTOP; ++u) {
        ck[u] = ~0u;
        if (u < fpn) {
          const unsigned va = (ia < KTOP) ? sf[0][ia] : 0u;
          const unsigned vb = (ib < KTOP) ? sf[1][ib] : 0u;
          unsigned m;
          if (va >= vb) { m = va; ++ia; } else { m = vb; ++ib; }
          if (m != 0u) { ck[u] = m; nc = u + 1; }
        }
      }
    }
    if (nc > 0) {                              // nc block-uniform
      int cnt[KTOP];
      #pragma unroll
      for (int u = 0; u < KTOP; ++u) cnt[u] = 0;
      #pragma unroll
      for (int e = 0; e < 32; ++e) {
        #pragma unroll
        for (int u = 0; u < KTOP; ++u) cnt[u] += (k[e] > ck[u]) ? 1 : 0;
      }
      #pragma unroll
      for (int u = 0; u < KTOP; ++u) {
        const int sc_ = wavesum_dpp(cnt[u]);
        if (lane == 0) scnt[h][u] = sc_;
      }
    }
    __syncthreads();   // [3] counts visible
    if (nc > 0) {
      #pragma unroll
      for (int u = 0; u < KTOP; ++u) {
        if (u < nc) {
          const int rank = 1 + scnt[0][u] + scnt[1][u];
          fn += ord16val(ck[u] >> 13) * (1.f / log2f((float)(rank + 1)) + 1.f);
        }
      }
    }
  }

  if (tid == 0) partials[row] = fp - fn;
}

// ---------------- K3: deterministic final reduction ----------------
__global__ __launch_bounds__(256) void finalreduce(const float* __restrict__ partials,
                                                   float* __restrict__ out) {
  __shared__ float s[256];
  const int tid = threadIdx.x;
  float acc = 0.f;
  for (int j = tid; j < BB; j += 256) acc += partials[j];
  s[tid] = acc; __syncthreads();
  #pragma unroll
  for (int st = 128; st; st >>= 1) { if (tid < st) s[tid] += s[tid + st]; __syncthreads(); }
  if (tid == 0) out[0] = s[0];
}

extern "C" void kernel_launch(void* const* d_in, const int* in_sizes, int n_in,
                              void* d_out, int out_size, void* d_ws, size_t ws_size,
                              hipStream_t stream) {
  const float* R      = (const float*)d_in[0];
  const int*   labels = (const int*)d_in[1];
  float* out = (float*)d_out;

  unsigned short* simq = (unsigned short*)d_ws;                          // 32 MB
  float* sq            = (float*)((char*)d_ws + (size_t)BB * BB * 2);    // 16 KB
  float* partials      = sq + BB;                                        // 16 KB

  splitsq<<<BB, 64, 0, stream>>>(R, sq);
  repack<<<BB / 16, 256, 0, stream>>>();
  buildmask<<<64, 64, 0, stream>>>(labels);
  simgemm_pk<<<NTRI, 256, 0, stream>>>(labels, sq, simq);
  rowproc10<<<BB, 128, 0, stream>>>(simq, labels, partials);
  finalreduce<<<1, 256, 0, stream>>>(partials, out);
}

// Round 25
// 88.799 us; speedup vs baseline: 1.0221x; 1.0221x over previous
//
#include <hip/hip_runtime.h>
#include <math.h>

#define BB 4096        // batch size
#define DD 512         // repr dim
#define KTOP 9         // K+1
#define MARGIN_F 0.2f
#define NT 32          // 4096/128
#define NTRI (NT * (NT + 1) / 2)   // 528 upper-triangle 128x128 blocks

typedef __attribute__((ext_vector_type(8))) short short8;
typedef __attribute__((ext_vector_type(4))) float f32x4;
typedef unsigned long long u64;

__device__ unsigned short g_Rhi[(size_t)BB * DD];
__device__ unsigned short g_Rpk[(size_t)BB * DD];   // panel-major MFMA-fragment layout
__device__ u64 g_cmask[64 * 64];   // [class][lane] bit e -> label[j(lane,e)]==class

// ---- bf16 helper (RNE) ----
__device__ __forceinline__ unsigned short f2bf(float x) {
  unsigned u = __float_as_uint(x);
  u += 0x7fffu + ((u >> 16) & 1u);
  return (unsigned short)(u >> 16);
}

// ---- 16-bit ord: monotone map of f32, truncated; dequant mid-bucket ----
__device__ __forceinline__ float ord16val(unsigned o16) {
  unsigned e = (o16 << 16) | 0x8000u;
  unsigned s = (e & 0x80000000u) ? (e ^ 0x80000000u) : ~e;
  return __uint_as_float(s);
}

// ---- DPP wave reductions ----
__device__ __forceinline__ unsigned wavemax32_dpp(unsigned c) {
#define MSTEP(CTRL, RM)                                                        \
  {                                                                            \
    unsigned o = (unsigned)__builtin_amdgcn_update_dpp(0, (int)c, CTRL, RM, 0xf, false); \
    if (o > c) c = o;                                                          \
  }
  MSTEP(0xB1, 0xf) MSTEP(0x4E, 0xf) MSTEP(0x141, 0xf) MSTEP(0x140, 0xf)
  MSTEP(0x142, 0xa) MSTEP(0x143, 0xc)
#undef MSTEP
  return (unsigned)__builtin_amdgcn_readlane((int)c, 63);
}

__device__ __forceinline__ int wavesum_dpp(int c) {
#define SSTEP(CTRL, RM)                                                        \
  c += __builtin_amdgcn_update_dpp(0, c, CTRL, RM, 0xf, false);
  SSTEP(0xB1, 0xf) SSTEP(0x4E, 0xf) SSTEP(0x141, 0xf) SSTEP(0x140, 0xf)
  SSTEP(0x142, 0xa) SSTEP(0x143, 0xc)
#undef SSTEP
  return __builtin_amdgcn_readlane(c, 63);
}

__device__ __forceinline__ unsigned u4c(const uint4& f, int q) {
  return q == 0 ? f.x : q == 1 ? f.y : q == 2 ? f.z : f.w;
}

// ---------------- K0: split R -> bf16 hi + row sqnorms ----------------
__global__ __launch_bounds__(64) void splitsq(const float* __restrict__ R,
                                              float* __restrict__ sq) {
  const int row = blockIdx.x, lane = threadIdx.x;
  const float4* r4 = (const float4*)(R + (size_t)row * DD);
  float4 a = r4[lane], b = r4[lane + 64];
  float xs[8] = {a.x, a.y, a.z, a.w, b.x, b.y, b.z, b.w};
  unsigned short hs[8];
  float s = 0.f;
  #pragma unroll
  for (int q = 0; q < 8; ++q) {
    float x = xs[q];
    s += x * x;
    hs[q] = f2bf(x);
  }
  const size_t base = (size_t)row * DD;
  *(ushort4*)&g_Rhi[base + lane * 4]       = *(ushort4*)&hs[0];
  *(ushort4*)&g_Rhi[base + 256 + lane * 4] = *(ushort4*)&hs[4];
  #pragma unroll
  for (int off = 32; off; off >>= 1) s += __shfl_down(s, off);
  if (lane == 0) sq[row] = s;
}

// ---------------- K0a: repack hi into panel-major MFMA fragment layout ----------------
__global__ __launch_bounds__(256) void repack(void) {
  const int p = blockIdx.x;
  #pragma unroll
  for (int i = 0; i < 4; ++i) {
    const int idx = i * 256 + threadIdx.x;
    const int ks = idx >> 6, l = idx & 63;
    const int row = p * 16 + (l & 15);
    const int k0 = ks * 32 + (l >> 4) * 8;
    *(uint4*)&g_Rpk[(size_t)p * 8192 + (size_t)idx * 8] =
        *(const uint4*)&g_Rhi[(size_t)row * DD + k0];
  }
}

// ---------------- K0b: per-class match bitmasks ----------------
__global__ __launch_bounds__(64) void buildmask(const int* __restrict__ labels) {
  __shared__ int slab[BB];
  const int c = blockIdx.x, lane = threadIdx.x;
  for (int i = lane; i < BB / 4; i += 64) ((int4*)slab)[i] = ((const int4*)labels)[i];
  __syncthreads();
  u64 m = 0;
  #pragma unroll
  for (int e = 0; e < 64; ++e) {
    int j = 512 * (e >> 3) + 8 * lane + (e & 7);
    m |= (u64)(slab[j] == c) << e;
  }
  g_cmask[c * 64 + lane] = m;
}

// ---------------- K1: panel-packed barrier-free MFMA GEMM, TRIPLE reg buffer ----------------
// R22's dbuf issues step s+1 loads after step s starts consuming -- serialized.
// Triple buffer: step s computes buf(s%3) while loads for s+1 AND s+2 are in
// flight (issued a full MFMA phase earlier). ~190 VGPR, fits (256,2). No LDS,
// no barriers in the K-loop.
__global__ __launch_bounds__(256, 2) void simgemm_pk3(const int* __restrict__ labels,
                                                      const float* __restrict__ sq,
                                                      unsigned short* __restrict__ simq) {
  const int x = blockIdx.x & 7;      // XCD (round-robin dispatch)
  int c = blockIdx.x >> 3;           // 0..65 within XCD
  int bi = 0, bj = 0;
  #pragma unroll
  for (int q = 0; q < 4; ++q) {
    const int bjq = (q < 2) ? (2 * x + q) : (28 - 2 * x + q);   // {2x,2x+1,30-2x,31-2x}
    const int n = bjq + 1;
    if (c >= 0 && c < n) { bj = bjq; bi = c; }
    c -= n;
  }
  const int i0 = bi * 128, j0 = bj * 128;

  __shared__ __align__(16) unsigned char smembytes[35840];   // epilogue only

  const int tid = threadIdx.x;
  const int wid = tid >> 6, lane = tid & 63;
  const int wr = wid >> 1, wc = wid & 1;
  const int lrow = lane & 15, kblk = lane >> 4;

  const unsigned short* pA[4];
  const unsigned short* pB[4];
  #pragma unroll
  for (int m = 0; m < 4; ++m) {
    pA[m] = g_Rpk + (size_t)(bi * 8 + wr * 4 + m) * 8192 + lane * 8;
    pB[m] = g_Rpk + (size_t)(bj * 8 + wc * 4 + m) * 8192 + lane * 8;
  }

  f32x4 acc[4][4] = {};
  short8 fa[3][4], fb[3][4];

  #pragma unroll
  for (int m = 0; m < 4; ++m) {
    fa[0][m] = *(const short8*)(pA[m]);
    fb[0][m] = *(const short8*)(pB[m]);
    fa[1][m] = *(const short8*)(pA[m] + 512);
    fb[1][m] = *(const short8*)(pB[m] + 512);
  }

  #pragma unroll
  for (int step = 0; step < 16; ++step) {
    const int cur = step % 3;
    if (step < 14) {
      const int nxt = (step + 2) % 3;
      const int koff = (step + 2) * 512;
      #pragma unroll
      for (int m = 0; m < 4; ++m) {
        fa[nxt][m] = *(const short8*)(pA[m] + koff);
        fb[nxt][m] = *(const short8*)(pB[m] + koff);
      }
    }
    #pragma unroll
    for (int m = 0; m < 4; ++m) {
      #pragma unroll
      for (int n = 0; n < 4; ++n) {
        acc[m][n] = __builtin_amdgcn_mfma_f32_16x16x32_bf16(fa[cur][m], fb[cur][n], acc[m][n], 0, 0, 0);
      }
    }
  }

  // ---- epilogue: quantize to u16 ord into LDS T[128][132], coalesced dual store ----
  unsigned short (*T)[132] = (unsigned short (*)[132])smembytes;   // 33792 B
  float* sqi = (float*)(smembytes + 33792);
  float* sqj = (float*)(smembytes + 34304);
  int* labi  = (int*)(smembytes + 34816);
  int* labj  = (int*)(smembytes + 35328);
  if (tid < 128) { sqi[tid] = sq[i0 + tid]; labi[tid] = labels[i0 + tid]; }
  else { int t2 = tid - 128; sqj[t2] = sq[j0 + t2]; labj[t2] = labels[j0 + t2]; }
  __syncthreads();

  #pragma unroll
  for (int m = 0; m < 4; ++m) {
    const int rbase = wr * 64 + m * 16 + kblk * 4;
    #pragma unroll
    for (int n = 0; n < 4; ++n) {
      const int ccol = wc * 64 + n * 16 + lrow;
      const float sqc = sqj[ccol];
      const int lc_ = labj[ccol];
      #pragma unroll
      for (int reg = 0; reg < 4; ++reg) {
        const int r = rbase + reg;
        float res = sqi[r] - 2.0f * acc[m][n][reg] + sqc;
        float dd = (res <= 0.f) ? 0.f : sqrtf(res);
        float sv = -dd + ((labi[r] != lc_) ? MARGIN_F : 0.f);
        unsigned su = __float_as_uint(sv);
        unsigned ord = su ^ ((unsigned)((int)su >> 31) | 0x80000000u);
        T[r][ccol] = (unsigned short)(ord >> 16);
      }
    }
  }
  __syncthreads();

  const int srow0 = tid >> 4, scol0 = (tid & 15) * 8;
  #pragma unroll
  for (int p = 0; p < 8; ++p) {
    const int r = p * 16 + srow0;
    short8 w = *(const short8*)&T[r][scol0];
    *(short8*)&simq[(size_t)(i0 + r) * BB + j0 + scol0] = w;
  }
  if (bi != bj) {
    #pragma unroll
    for (int p = 0; p < 8; ++p) {
      const int col = p * 16 + srow0;
      unsigned short tmp[8];
      #pragma unroll
      for (int t = 0; t < 8; ++t) tmp[t] = T[scol0 + t][col];
      *(short8*)&simq[(size_t)(j0 + col) * BB + i0 + scol0] = *(short8*)tmp;
    }
  }
}

// ---------------- K2: rank processing, TWO waves per row (R21/R22 best-known) ----------------
#define TOP2UPD(k, a, b) {                                                     \
  unsigned _mx = ((k) > (a)) ? (k) : (a);                                      \
  unsigned _mn = ((k) > (a)) ? (a) : (k);                                      \
  (a) = _mx;                                                                   \
  (b) = (_mn > (b)) ? _mn : (b); }

__global__ __launch_bounds__(128) void rowproc9(const unsigned short* __restrict__ simq,
                                                const int* __restrict__ labels,
                                                float* __restrict__ partials) {
  __shared__ unsigned sred[2 * KTOP + 2][2];
  __shared__ int sint[2 + 2 * KTOP];          // spos[2] | scnt[2][KTOP]

  const int tid = threadIdx.x;
  const int lane = tid & 63;
  const int h = tid >> 6;                     // wave 0/1
  const int row = blockIdx.x;

  const uint4* rp = (const uint4*)(simq + (size_t)row * BB);
  uint4 w0 = rp[lane + (4 * h + 0) * 64];
  uint4 w1 = rp[lane + (4 * h + 1) * 64];
  uint4 w2 = rp[lane + (4 * h + 2) * 64];
  uint4 w3 = rp[lane + (4 * h + 3) * 64];

  const int myl = labels[row];
  const unsigned mh = (unsigned)(g_cmask[myl * 64 + lane] >> (32 * h));
  const unsigned lbase2 = (unsigned)((4095 - 8 * lane) << 1);

  unsigned k[32];
  #pragma unroll
  for (int s = 0; s < 4; ++s) {
    const uint4 w = s == 0 ? w0 : s == 1 ? w1 : s == 2 ? w2 : w3;
    const unsigned base_s = lbase2 - (unsigned)(1024 * (4 * h + s));
    #pragma unroll
    for (int q = 0; q < 4; ++q) {
      const unsigned wv = u4c(w, q);
      const int e0 = s * 8 + q * 2;
      k[e0]     = ((wv & 0xffffu) << 13)
                | (base_s - (unsigned)((q * 2) << 1)     + ((mh >> e0) & 1u));
      k[e0 + 1] = ((wv >> 16) << 13)
                | (base_s - (unsigned)((q * 2 + 1) << 1) + ((mh >> (e0 + 1)) & 1u));
    }
  }

  {
    int p = wavesum_dpp(__popc(mh));
    sint[h] = p;
  }
  __syncthreads();
  const int pos = sint[0] + sint[1];
  const int ks = min(pos, KTOP);

  unsigned h1 = 0, h2 = 0;
  #pragma unroll
  for (int e = 0; e < 32; ++e) TOP2UPD(k[e], h1, h2);

  unsigned kth = 0;
  float fp = 0.f; int fpn = 0;
  #pragma unroll
  for (int t = 0; t < KTOP; ++t) {
    if (t < ks) {
      sred[t][h] = wavemax32_dpp(h1);
    }
    __syncthreads();
    if (t < ks) {
      const unsigned g = max(sred[t][0], sred[t][1]);
      if (!(g & 1u)) { fp += ord16val(g >> 13) * (1.f / log2f((float)(t + 2)) + 1.f); fpn++; }
      if (t == ks - 1) kth = g;
      if (h1 == g) {
        h1 = h2; h2 = ~0u;
        if (h1 == ~0u) {
          h1 = 0; h2 = 0;
          #pragma unroll
          for (int e = 0; e < 32; ++e) {
            if (k[e] < g) TOP2UPD(k[e], h1, h2);
          }
        }
      }
    }
  }

  float fn = 0.f;
  if (fpn > 0) {
    unsigned f1 = 0, f2 = 0;
    #pragma unroll
    for (int e = 0; e < 32; ++e) {
      if ((k[e] & 1u) && k[e] < kth) TOP2UPD(k[e], f1, f2);
    }
    unsigned ck[KTOP];
    int nc = 0;
    #pragma unroll
    for (int u = 0; u < KTOP; ++u) {
      ck[u] = ~0u;
      if (u < fpn) {
        sred[KTOP + 1 + u][h] = wavemax32_dpp(f1);
      }
      __syncthreads();
      if (u < fpn) {
        const unsigned g = max(sred[KTOP + 1 + u][0], sred[KTOP + 1 + u][1]);
        if (g != 0u) {
          ck[u] = g; nc = u + 1;
          if (f1 == g) {
            f1 = f2; f2 = ~0u;
            if (f1 == ~0u) {
              f1 = 0; f2 = 0;
              #pragma unroll
              for (int e = 0; e < 32; ++e) {
                if ((k[e] & 1u) && k[e] < g) TOP2UPD(k[e], f1, f2);
              }
            }
          }
        }
      }
    }
    if (nc > 0) {
      int cnt[KTOP];
      #pragma unroll
      for (int u = 0; u < KTOP; ++u) cnt[u] = 0;
      #pragma unroll
      for (int e = 0; e < 32; ++e) {
        #pragma unroll
        for (int u = 0; u < KTOP; ++u) cnt[u] += (k[e] > ck[u]) ? 1 : 0;
      }
      #pragma unroll
      for (int u = 0; u < KTOP; ++u) {
        sint[2 + h * KTOP + u] = wavesum_dpp(cnt[u]);
      }
    }
    __syncthreads();
    if (nc > 0) {
      #pragma unroll
      for (int u = 0; u < KTOP; ++u) {
        if (u < nc) {
          const int rank = 1 + sint[2 + u] + sint[2 + KTOP + u];
          fn += ord16val(ck[u] >> 13) * (1.f / log2f((float)(rank + 1)) + 1.f);
        }
      }
    }
  }

  if (tid == 0) partials[row] = fp - fn;
}

// ---------------- K3: deterministic final reduction ----------------
__global__ __launch_bounds__(256) void finalreduce(const float* __restrict__ partials,
                                                   float* __restrict__ out) {
  __shared__ float s[256];
  const int tid = threadIdx.x;
  float acc = 0.f;
  for (int j = tid; j < BB; j += 256) acc += partials[j];
  s[tid] = acc; __syncthreads();
  #pragma unroll
  for (int st = 128; st; st >>= 1) { if (tid < st) s[tid] += s[tid + st]; __syncthreads(); }
  if (tid == 0) out[0] = s[0];
}

extern "C" void kernel_launch(void* const* d_in, const int* in_sizes, int n_in,
                              void* d_out, int out_size, void* d_ws, size_t ws_size,
                              hipStream_t stream) {
  const float* R      = (const float*)d_in[0];
  const int*   labels = (const int*)d_in[1];
  float* out = (float*)d_out;

  unsigned short* simq = (unsigned short*)d_ws;                          // 32 MB
  float* sq            = (float*)((char*)d_ws + (size_t)BB * BB * 2);    // 16 KB
  float* partials      = sq + BB;                                        // 16 KB

  splitsq<<<BB, 64, 0, stream>>>(R, sq);
  repack<<<BB / 16, 256, 0, stream>>>();
  buildmask<<<64, 64, 0, stream>>>(labels);
  simgemm_pk3<<<NTRI, 256, 0, stream>>>(labels, sq, simq);
  rowproc9<<<BB, 128, 0, stream>>>(simq, labels, partials);
  finalreduce<<<1, 256, 0, stream>>>(partials, out);
}

// Round 26
// 86.069 us; speedup vs baseline: 1.0545x; 1.0317x over previous
//
#include <hip/hip_runtime.h>
#include <math.h>

#define BB 4096        // batch size
#define DD 512         // repr dim
#define KTOP 9         // K+1
#define MARGIN_F 0.2f
#define NT 32          // 4096/128
#define NTRI (NT * (NT + 1) / 2)   // 528 upper-triangle 128x128 blocks

typedef __attribute__((ext_vector_type(8))) short short8;
typedef __attribute__((ext_vector_type(4))) float f32x4;
typedef unsigned long long u64;

__device__ unsigned short g_Rpk[(size_t)BB * DD];   // panel-major MFMA-fragment layout
__device__ u64 g_cmask[64 * 64];   // [class][lane] bit e -> label[j(lane,e)]==class

// ---- bf16 helper (RNE) ----
__device__ __forceinline__ unsigned short f2bf(float x) {
  unsigned u = __float_as_uint(x);
  u += 0x7fffu + ((u >> 16) & 1u);
  return (unsigned short)(u >> 16);
}

// ---- 16-bit ord: monotone map of f32, truncated; dequant mid-bucket ----
__device__ __forceinline__ float ord16val(unsigned o16) {
  unsigned e = (o16 << 16) | 0x8000u;
  unsigned s = (e & 0x80000000u) ? (e ^ 0x80000000u) : ~e;
  return __uint_as_float(s);
}

// ---- DPP wave reductions ----
__device__ __forceinline__ unsigned wavemax32_dpp(unsigned c) {
#define MSTEP(CTRL, RM)                                                        \
  {                                                                            \
    unsigned o = (unsigned)__builtin_amdgcn_update_dpp(0, (int)c, CTRL, RM, 0xf, false); \
    if (o > c) c = o;                                                          \
  }
  MSTEP(0xB1, 0xf) MSTEP(0x4E, 0xf) MSTEP(0x141, 0xf) MSTEP(0x140, 0xf)
  MSTEP(0x142, 0xa) MSTEP(0x143, 0xc)
#undef MSTEP
  return (unsigned)__builtin_amdgcn_readlane((int)c, 63);
}

__device__ __forceinline__ int wavesum_dpp(int c) {
#define SSTEP(CTRL, RM)                                                        \
  c += __builtin_amdgcn_update_dpp(0, c, CTRL, RM, 0xf, false);
  SSTEP(0xB1, 0xf) SSTEP(0x4E, 0xf) SSTEP(0x141, 0xf) SSTEP(0x140, 0xf)
  SSTEP(0x142, 0xa) SSTEP(0x143, 0xc)
#undef SSTEP
  return __builtin_amdgcn_readlane(c, 63);
}

__device__ __forceinline__ unsigned u4c(const uint4& f, int q) {
  return q == 0 ? f.x : q == 1 ? f.y : q == 2 ? f.z : f.w;
}

// ---------------- K0: fused split+pack (panel-major) + row sqnorms ----------------
// One block per 16-row panel. Item idx (0..1023): ks=idx>>6, l=idx&63 ->
// 8 floats from row p*16+(l&15), k=ks*32+((l>>4)&3)*8; bf16-convert; write
// pk[p*8192+idx*8] (threads write 16B contiguous -> fully coalesced).
// Thread t's 4 items (t+256i) all have idx&15==t&15 -> per-row partial sums
// fold in a 16x16 LDS tile. Replaces splitsq+repack (20 MB -> 12 MB traffic).
__global__ __launch_bounds__(256) void packsq(const float* __restrict__ R,
                                              float* __restrict__ sq) {
  __shared__ float part[16][17];
  const int p = blockIdx.x;
  const int t = threadIdx.x;

  float s = 0.f;
  #pragma unroll
  for (int i = 0; i < 4; ++i) {
    const int idx = t + 256 * i;
    const int ks = idx >> 6, l = idx & 63;
    const int row = p * 16 + (l & 15);
    const int k0 = ks * 32 + ((l >> 4) & 3) * 8;
    const float4 a = *(const float4*)&R[(size_t)row * DD + k0];
    const float4 b = *(const float4*)&R[(size_t)row * DD + k0 + 4];
    float xs[8] = {a.x, a.y, a.z, a.w, b.x, b.y, b.z, b.w};
    unsigned short hs[8];
    #pragma unroll
    for (int q = 0; q < 8; ++q) {
      s += xs[q] * xs[q];
      hs[q] = f2bf(xs[q]);
    }
    *(uint4*)&g_Rpk[(size_t)p * 8192 + (size_t)idx * 8] = *(uint4*)hs;
  }
  part[t & 15][t >> 4] = s;
  __syncthreads();
  if (t < 16) {
    float tot = 0.f;
    #pragma unroll
    for (int i = 0; i < 16; ++i) tot += part[t][i];
    sq[p * 16 + t] = tot;
  }
}

// ---------------- K0b: per-class match bitmasks ----------------
__global__ __launch_bounds__(64) void buildmask(const int* __restrict__ labels) {
  __shared__ int slab[BB];
  const int c = blockIdx.x, lane = threadIdx.x;
  for (int i = lane; i < BB / 4; i += 64) ((int4*)slab)[i] = ((const int4*)labels)[i];
  __syncthreads();
  u64 m = 0;
  #pragma unroll
  for (int e = 0; e < 64; ++e) {
    int j = 512 * (e >> 3) + 8 * lane + (e & 7);
    m |= (u64)(slab[j] == c) << e;
  }
  g_cmask[c * 64 + lane] = m;
}

// ---------------- K1: panel-packed barrier-free MFMA GEMM, triple reg buffer ----------------
__global__ __launch_bounds__(256, 2) void simgemm_pk3(const int* __restrict__ labels,
                                                      const float* __restrict__ sq,
                                                      unsigned short* __restrict__ simq) {
  const int x = blockIdx.x & 7;      // XCD (round-robin dispatch)
  int c = blockIdx.x >> 3;           // 0..65 within XCD
  int bi = 0, bj = 0;
  #pragma unroll
  for (int q = 0; q < 4; ++q) {
    const int bjq = (q < 2) ? (2 * x + q) : (28 - 2 * x + q);   // {2x,2x+1,30-2x,31-2x}
    const int n = bjq + 1;
    if (c >= 0 && c < n) { bj = bjq; bi = c; }
    c -= n;
  }
  const int i0 = bi * 128, j0 = bj * 128;

  __shared__ __align__(16) unsigned char smembytes[35840];   // epilogue only

  const int tid = threadIdx.x;
  const int wid = tid >> 6, lane = tid & 63;
  const int wr = wid >> 1, wc = wid & 1;
  const int lrow = lane & 15, kblk = lane >> 4;

  const unsigned short* pA[4];
  const unsigned short* pB[4];
  #pragma unroll
  for (int m = 0; m < 4; ++m) {
    pA[m] = g_Rpk + (size_t)(bi * 8 + wr * 4 + m) * 8192 + lane * 8;
    pB[m] = g_Rpk + (size_t)(bj * 8 + wc * 4 + m) * 8192 + lane * 8;
  }

  f32x4 acc[4][4] = {};
  short8 fa[3][4], fb[3][4];

  #pragma unroll
  for (int m = 0; m < 4; ++m) {
    fa[0][m] = *(const short8*)(pA[m]);
    fb[0][m] = *(const short8*)(pB[m]);
    fa[1][m] = *(const short8*)(pA[m] + 512);
    fb[1][m] = *(const short8*)(pB[m] + 512);
  }

  #pragma unroll
  for (int step = 0; step < 16; ++step) {
    const int cur = step % 3;
    if (step < 14) {
      const int nxt = (step + 2) % 3;
      const int koff = (step + 2) * 512;
      #pragma unroll
      for (int m = 0; m < 4; ++m) {
        fa[nxt][m] = *(const short8*)(pA[m] + koff);
        fb[nxt][m] = *(const short8*)(pB[m] + koff);
      }
    }
    #pragma unroll
    for (int m = 0; m < 4; ++m) {
      #pragma unroll
      for (int n = 0; n < 4; ++n) {
        acc[m][n] = __builtin_amdgcn_mfma_f32_16x16x32_bf16(fa[cur][m], fb[cur][n], acc[m][n], 0, 0, 0);
      }
    }
  }

  // ---- epilogue: quantize to u16 ord into LDS T[128][132], coalesced dual store ----
  unsigned short (*T)[132] = (unsigned short (*)[132])smembytes;   // 33792 B
  float* sqi = (float*)(smembytes + 33792);
  float* sqj = (float*)(smembytes + 34304);
  int* labi  = (int*)(smembytes + 34816);
  int* labj  = (int*)(smembytes + 35328);
  if (tid < 128) { sqi[tid] = sq[i0 + tid]; labi[tid] = labels[i0 + tid]; }
  else { int t2 = tid - 128; sqj[t2] = sq[j0 + t2]; labj[t2] = labels[j0 + t2]; }
  __syncthreads();

  #pragma unroll
  for (int m = 0; m < 4; ++m) {
    const int rbase = wr * 64 + m * 16 + kblk * 4;
    #pragma unroll
    for (int n = 0; n < 4; ++n) {
      const int ccol = wc * 64 + n * 16 + lrow;
      const float sqc = sqj[ccol];
      const int lc_ = labj[ccol];
      #pragma unroll
      for (int reg = 0; reg < 4; ++reg) {
        const int r = rbase + reg;
        float res = sqi[r] - 2.0f * acc[m][n][reg] + sqc;
        float dd = (res <= 0.f) ? 0.f : sqrtf(res);
        float sv = -dd + ((labi[r] != lc_) ? MARGIN_F : 0.f);
        unsigned su = __float_as_uint(sv);
        unsigned ord = su ^ ((unsigned)((int)su >> 31) | 0x80000000u);
        T[r][ccol] = (unsigned short)(ord >> 16);
      }
    }
  }
  __syncthreads();

  const int srow0 = tid >> 4, scol0 = (tid & 15) * 8;
  #pragma unroll
  for (int p = 0; p < 8; ++p) {
    const int r = p * 16 + srow0;
    short8 w = *(const short8*)&T[r][scol0];
    *(short8*)&simq[(size_t)(i0 + r) * BB + j0 + scol0] = w;
  }
  if (bi != bj) {
    #pragma unroll
    for (int p = 0; p < 8; ++p) {
      const int col = p * 16 + srow0;
      unsigned short tmp[8];
      #pragma unroll
      for (int t = 0; t < 8; ++t) tmp[t] = T[scol0 + t][col];
      *(short8*)&simq[(size_t)(j0 + col) * BB + i0 + scol0] = *(short8*)tmp;
    }
  }
}

// ---------------- K2: rank processing, TWO waves per row (best-known) ----------------
#define TOP2UPD(k, a, b) {                                                     \
  unsigned _mx = ((k) > (a)) ? (k) : (a);                                      \
  unsigned _mn = ((k) > (a)) ? (a) : (k);                                      \
  (a) = _mx;                                                                   \
  (b) = (_mn > (b)) ? _mn : (b); }

__global__ __launch_bounds__(128) void rowproc9(const unsigned short* __restrict__ simq,
                                                const int* __restrict__ labels,
                                                float* __restrict__ partials) {
  __shared__ unsigned sred[2 * KTOP + 2][2];
  __shared__ int sint[2 + 2 * KTOP];          // spos[2] | scnt[2][KTOP]

  const int tid = threadIdx.x;
  const int lane = tid & 63;
  const int h = tid >> 6;                     // wave 0/1
  const int row = blockIdx.x;

  const uint4* rp = (const uint4*)(simq + (size_t)row * BB);
  uint4 w0 = rp[lane + (4 * h + 0) * 64];
  uint4 w1 = rp[lane + (4 * h + 1) * 64];
  uint4 w2 = rp[lane + (4 * h + 2) * 64];
  uint4 w3 = rp[lane + (4 * h + 3) * 64];

  const int myl = labels[row];
  const unsigned mh = (unsigned)(g_cmask[myl * 64 + lane] >> (32 * h));
  const unsigned lbase2 = (unsigned)((4095 - 8 * lane) << 1);

  unsigned k[32];
  #pragma unroll
  for (int s = 0; s < 4; ++s) {
    const uint4 w = s == 0 ? w0 : s == 1 ? w1 : s == 2 ? w2 : w3;
    const unsigned base_s = lbase2 - (unsigned)(1024 * (4 * h + s));
    #pragma unroll
    for (int q = 0; q < 4; ++q) {
      const unsigned wv = u4c(w, q);
      const int e0 = s * 8 + q * 2;
      k[e0]     = ((wv & 0xffffu) << 13)
                | (base_s - (unsigned)((q * 2) << 1)     + ((mh >> e0) & 1u));
      k[e0 + 1] = ((wv >> 16) << 13)
                | (base_s - (unsigned)((q * 2 + 1) << 1) + ((mh >> (e0 + 1)) & 1u));
    }
  }

  {
    int p = wavesum_dpp(__popc(mh));
    sint[h] = p;
  }
  __syncthreads();
  const int pos = sint[0] + sint[1];
  const int ks = min(pos, KTOP);

  unsigned h1 = 0, h2 = 0;
  #pragma unroll
  for (int e = 0; e < 32; ++e) TOP2UPD(k[e], h1, h2);

  unsigned kth = 0;
  float fp = 0.f; int fpn = 0;
  #pragma unroll
  for (int t = 0; t < KTOP; ++t) {
    if (t < ks) {
      sred[t][h] = wavemax32_dpp(h1);
    }
    __syncthreads();
    if (t < ks) {
      const unsigned g = max(sred[t][0], sred[t][1]);
      if (!(g & 1u)) { fp += ord16val(g >> 13) * (1.f / log2f((float)(t + 2)) + 1.f); fpn++; }
      if (t == ks - 1) kth = g;
      if (h1 == g) {
        h1 = h2; h2 = ~0u;
        if (h1 == ~0u) {
          h1 = 0; h2 = 0;
          #pragma unroll
          for (int e = 0; e < 32; ++e) {
            if (k[e] < g) TOP2UPD(k[e], h1, h2);
          }
        }
      }
    }
  }

  float fn = 0.f;
  if (fpn > 0) {
    unsigned f1 = 0, f2 = 0;
    #pragma unroll
    for (int e = 0; e < 32; ++e) {
      if ((k[e] & 1u) && k[e] < kth) TOP2UPD(k[e], f1, f2);
    }
    unsigned ck[KTOP];
    int nc = 0;
    #pragma unroll
    for (int u = 0; u < KTOP; ++u) {
      ck[u] = ~0u;
      if (u < fpn) {
        sred[KTOP + 1 + u][h] = wavemax32_dpp(f1);
      }
      __syncthreads();
      if (u < fpn) {
        const unsigned g = max(sred[KTOP + 1 + u][0], sred[KTOP + 1 + u][1]);
        if (g != 0u) {
          ck[u] = g; nc = u + 1;
          if (f1 == g) {
            f1 = f2; f2 = ~0u;
            if (f1 == ~0u) {
              f1 = 0; f2 = 0;
              #pragma unroll
              for (int e = 0; e < 32; ++e) {
                if ((k[e] & 1u) && k[e] < g) TOP2UPD(k[e], f1, f2);
              }
            }
          }
        }
      }
    }
    if (nc > 0) {
      int cnt[KTOP];
      #pragma unroll
      for (int u = 0; u < KTOP; ++u) cnt[u] = 0;
      #pragma unroll
      for (int e = 0; e < 32; ++e) {
        #pragma unroll
        for (int u = 0; u < KTOP; ++u) cnt[u] += (k[e] > ck[u]) ? 1 : 0;
      }
      #pragma unroll
      for (int u = 0; u < KTOP; ++u) {
        sint[2 + h * KTOP + u] = wavesum_dpp(cnt[u]);
      }
    }
    __syncthreads();
    if (nc > 0) {
      #pragma unroll
      for (int u = 0; u < KTOP; ++u) {
        if (u < nc) {
          const int rank = 1 + sint[2 + u] + sint[2 + KTOP + u];
          fn += ord16val(ck[u] >> 13) * (1.f / log2f((float)(rank + 1)) + 1.f);
        }
      }
    }
  }

  if (tid == 0) partials[row] = fp - fn;
}

// ---------------- K3: deterministic final reduction ----------------
__global__ __launch_bounds__(256) void finalreduce(const float* __restrict__ partials,
                                                   float* __restrict__ out) {
  __shared__ float s[256];
  const int tid = threadIdx.x;
  float acc = 0.f;
  for (int j = tid; j < BB; j += 256) acc += partials[j];
  s[tid] = acc; __syncthreads();
  #pragma unroll
  for (int st = 128; st; st >>= 1) { if (tid < st) s[tid] += s[tid + st]; __syncthreads(); }
  if (tid == 0) out[0] = s[0];
}

extern "C" void kernel_launch(void* const* d_in, const int* in_sizes, int n_in,
                              void* d_out, int out_size, void* d_ws, size_t ws_size,
                              hipStream_t stream) {
  const float* R      = (const float*)d_in[0];
  const int*   labels = (const int*)d_in[1];
  float* out = (float*)d_out;

  unsigned short* simq = (unsigned short*)d_ws;                          // 32 MB
  float* sq            = (float*)((char*)d_ws + (size_t)BB * BB * 2);    // 16 KB
  float* partials      = sq + BB;                                        // 16 KB

  packsq<<<BB / 16, 256, 0, stream>>>(R, sq);
  buildmask<<<64, 64, 0, stream>>>(labels);
  simgemm_pk3<<<NTRI, 256, 0, stream>>>(labels, sq, simq);
  rowproc9<<<BB, 128, 0, stream>>>(simq, labels, partials);
  finalreduce<<<1, 256, 0, stream>>>(partials, out);
}